// Round 14
// baseline (286.011 us; speedup 1.0000x reference)
//
#include <hip/hip_runtime.h>
#include <hip/hip_bf16.h>

#define HEADS 16
#define B_    8
#define H_    2048
#define L_    1024
#define DK    128   // H_/HEADS

typedef __attribute__((ext_vector_type(8))) __bf16 bf16x8;
typedef __attribute__((ext_vector_type(4))) float  f32x4;

// ---------------------------------------------------------------------------
// Kernel 0 (merged preps).
// Blocks 0..127:   qs2[bh][j] = { q.Wq + bias, score[j] }  (float2)
// Blocks 128..143: wktf fragment-order pack of Wk (bf16):
//   wktf[(nc*256 + ks*64 + lane)*8 + i] = Wk[k][n],
//   n = nc*16 + (lane&15), k = ks*32 + (lane>>4)*8 + i
// ---------------------------------------------------------------------------
__global__ void __launch_bounds__(256)
prep_kernel(const float* __restrict__ query,
            const float* __restrict__ attn_w,
            const float* __restrict__ bias,
            const float* __restrict__ score,
            float2* __restrict__ qs2,
            __bf16* __restrict__ wktf) {
  const int tid = threadIdx.x;
  if (blockIdx.x < 128) {
    const int jt = blockIdx.x & 7;    // j-tile
    const int bg = blockIdx.x >> 3;   // bh-group of 8
    __shared__ float qv[8][DK];
    for (int i = tid; i < 8 * DK; i += 256) {
      const int bh = bg * 8 + (i >> 7);
      const int d  = i & 127;
      const int b = bh >> 4, head = bh & 15;
      qv[i >> 7][d] = query[b * H_ + head * DK + d];
    }
    __syncthreads();
    const int j = jt * 256 + tid;
    const float bj = bias[j];
    const float sj = score[j];
    float acc[8];
#pragma unroll
    for (int u = 0; u < 8; ++u) acc[u] = bj;
    for (int d = 0; d < DK; ++d) {
      const float wv = attn_w[d * H_ + j];
#pragma unroll
      for (int u = 0; u < 8; ++u) acc[u] += qv[u][d] * wv;
    }
#pragma unroll
    for (int u = 0; u < 8; ++u) {
      float2 t; t.x = acc[u]; t.y = sj;
      qs2[(size_t)(bg * 8 + u) * H_ + j] = t;
    }
  } else {
    const int t0 = (blockIdx.x - 128) * 256 + tid;   // 0..4095
    for (int tt = t0; tt < 32768; tt += 4096) {
      const int lane2  = tt & 63;
      const int chunk2 = tt >> 6;
      const int ks = chunk2 & 3;
      const int nc = chunk2 >> 2;
      const int row = lane2 & 15, g = lane2 >> 4;
      const int n  = nc * 16 + row;
      const int k0 = ks * 32 + g * 8;
      bf16x8 v;
#pragma unroll
      for (int i = 0; i < 8; ++i)
        v[i] = (__bf16)attn_w[(size_t)(DK + k0 + i) * H_ + n];
      *(bf16x8*)(wktf + (size_t)tt * 8) = v;
    }
  }
}

// ---------------------------------------------------------------------------
// Kernel 1: partial logits over one H-half.
// NO LDS, NO barriers. Block = 4 fully independent waves x 64 rows; each
// block covers 64 n-chunks (one half). aF[4][4] resident (64 VGPR).
// B + {qwb,score} stream L2->registers, 2-stage pipeline pinned by
// sched_barrier(0). Grid (4,128,2) = 1024 blocks -> 4 blocks/CU ->
// 4 free-running waves/SIMD; launch_bounds(256,4) caps VGPR at 128
// (live set ~126: aF 64 + lacc 16 + 2x18 buffers + addressing).
// ---------------------------------------------------------------------------
__global__ void __launch_bounds__(256, 4)
logits_kernel(const float* __restrict__ feed,
              const __bf16* __restrict__ wktf,
              const float2* __restrict__ qs2,
              float* __restrict__ logits) {
  const int ltile = blockIdx.x;     // 0..3 (256 rows each)
  const int bh    = blockIdx.y;     // 0..127
  const int nblk  = blockIdx.z;     // 0..1 (H halves)
  const int b     = bh >> 4;
  const int head  = bh & 15;
  const int tid   = threadIdx.x;
  const int wave  = tid >> 6;
  const int lane  = tid & 63;
  const int row   = lane & 15;      // A row / B col / D col
  const int g     = lane >> 4;      // k-group 0..3

  // ---- A fragments: 4 subtiles x 4 k-steps, resident in registers ----
  bf16x8 aF[4][4];
#pragma unroll
  for (int s = 0; s < 4; ++s) {
    const int l = ltile * 256 + wave * 64 + s * 16 + row;
    const float* fh = feed + (size_t)l * (B_ * H_) + b * H_ + head * DK;
#pragma unroll
    for (int ks = 0; ks < 4; ++ks) {
      const int k0 = ks * 32 + g * 8;
      float4 x = *(const float4*)(fh + k0);
      float4 y = *(const float4*)(fh + k0 + 4);
      bf16x8 t;
      t[0] = (__bf16)x.x; t[1] = (__bf16)x.y; t[2] = (__bf16)x.z; t[3] = (__bf16)x.w;
      t[4] = (__bf16)y.x; t[5] = (__bf16)y.y; t[6] = (__bf16)y.z; t[7] = (__bf16)y.w;
      aF[s][ks] = t;
    }
  }

  // per-half bases: 64 chunks x 4KB = 256KB = 16384 bf16x8
  const bf16x8* wb = (const bf16x8*)wktf + (size_t)nblk * 16384 + lane;
  const float2* qp = qs2 + (size_t)bh * H_ + nblk * 1024 + row;

  float lacc[4][4] = {};
  bf16x8 a0, a1, a2, a3, b0, b1, b2, b3;
  float2 qA, qB;

#define LOADC(c_, x0_, x1_, x2_, x3_, q_) {                                   \
    const bf16x8* p = wb + (size_t)(c_) * 256;                                \
    x0_ = p[0]; x1_ = p[64]; x2_ = p[128]; x3_ = p[192];                      \
    q_ = qp[(c_) * 16];                                                       \
  }

#define COMPC(x0_, x1_, x2_, x3_, q_) {                                       \
    const float qx = q_.x, qy = q_.y;                                         \
    f32x4 d0 = {qx, qx, qx, qx};                                              \
    f32x4 d1 = {qx, qx, qx, qx};                                              \
    f32x4 d2 = {qx, qx, qx, qx};                                              \
    f32x4 d3 = {qx, qx, qx, qx};                                              \
    d0 = __builtin_amdgcn_mfma_f32_16x16x32_bf16(aF[0][0], x0_, d0, 0, 0, 0); \
    d1 = __builtin_amdgcn_mfma_f32_16x16x32_bf16(aF[1][0], x0_, d1, 0, 0, 0); \
    d2 = __builtin_amdgcn_mfma_f32_16x16x32_bf16(aF[2][0], x0_, d2, 0, 0, 0); \
    d3 = __builtin_amdgcn_mfma_f32_16x16x32_bf16(aF[3][0], x0_, d3, 0, 0, 0); \
    d0 = __builtin_amdgcn_mfma_f32_16x16x32_bf16(aF[0][1], x1_, d0, 0, 0, 0); \
    d1 = __builtin_amdgcn_mfma_f32_16x16x32_bf16(aF[1][1], x1_, d1, 0, 0, 0); \
    d2 = __builtin_amdgcn_mfma_f32_16x16x32_bf16(aF[2][1], x1_, d2, 0, 0, 0); \
    d3 = __builtin_amdgcn_mfma_f32_16x16x32_bf16(aF[3][1], x1_, d3, 0, 0, 0); \
    d0 = __builtin_amdgcn_mfma_f32_16x16x32_bf16(aF[0][2], x2_, d0, 0, 0, 0); \
    d1 = __builtin_amdgcn_mfma_f32_16x16x32_bf16(aF[1][2], x2_, d1, 0, 0, 0); \
    d2 = __builtin_amdgcn_mfma_f32_16x16x32_bf16(aF[2][2], x2_, d2, 0, 0, 0); \
    d3 = __builtin_amdgcn_mfma_f32_16x16x32_bf16(aF[3][2], x2_, d3, 0, 0, 0); \
    d0 = __builtin_amdgcn_mfma_f32_16x16x32_bf16(aF[0][3], x3_, d0, 0, 0, 0); \
    d1 = __builtin_amdgcn_mfma_f32_16x16x32_bf16(aF[1][3], x3_, d1, 0, 0, 0); \
    d2 = __builtin_amdgcn_mfma_f32_16x16x32_bf16(aF[2][3], x3_, d2, 0, 0, 0); \
    d3 = __builtin_amdgcn_mfma_f32_16x16x32_bf16(aF[3][3], x3_, d3, 0, 0, 0); \
    _Pragma("unroll")                                                         \
    for (int i = 0; i < 4; ++i) {                                             \
      lacc[0][i] += fmaxf(d0[i], 0.f) * qy;                                   \
      lacc[1][i] += fmaxf(d1[i], 0.f) * qy;                                   \
      lacc[2][i] += fmaxf(d2[i], 0.f) * qy;                                   \
      lacc[3][i] += fmaxf(d3[i], 0.f) * qy;                                   \
    }                                                                         \
  }

  LOADC(0, a0, a1, a2, a3, qA);
#pragma unroll 1
  for (int c = 0; c < 64; c += 2) {
    LOADC(c + 1, b0, b1, b2, b3, qB);
    __builtin_amdgcn_sched_barrier(0);    // prefetch stays ABOVE this compute
    COMPC(a0, a1, a2, a3, qA);
    const int cn = (c + 2 < 64) ? c + 2 : 63;  // tail: redundant, harmless
    LOADC(cn, a0, a1, a2, a3, qA);
    __builtin_amdgcn_sched_barrier(0);
    COMPC(b0, b1, b2, b3, qB);
  }

  // ---- reduce over the 16 D-columns, write partial logits ----
#pragma unroll
  for (int s = 0; s < 4; ++s) {
#pragma unroll
    for (int i = 0; i < 4; ++i) {
      float v = lacc[s][i];
#pragma unroll
      for (int off = 1; off < 16; off <<= 1) v += __shfl_xor(v, off);
      lacc[s][i] = v;
    }
  }
  if (row == 0) {
    float* lout = logits + (size_t)nblk * (128 * L_);
#pragma unroll
    for (int s = 0; s < 4; ++s) {
      const int base = bh * L_ + ltile * 256 + wave * 64 + s * 16 + g * 4;
#pragma unroll
      for (int i = 0; i < 4; ++i) lout[base + i] = lacc[s][i];
    }
  }
}

// ---------------------------------------------------------------------------
// Kernel 2: grid (bh, dpart): softmax over L (sum of the two H-half partial
// buffers, redundant per dpart), then out[d] over 32 d-columns. float4 reads.
// ---------------------------------------------------------------------------
__global__ void __launch_bounds__(256)
softmax_pv_kernel(const float* __restrict__ logits,
                  const float* __restrict__ values,
                  float* __restrict__ out) {
  const int bh    = blockIdx.x;   // 0..127
  const int dpart = blockIdx.y;   // 0..3  (32 d-cols each)
  const int b     = bh >> 4;
  const int head  = bh & 15;
  const int tid   = threadIdx.x;

  __shared__ float  sl[L_];
  __shared__ float  sred[4];
  __shared__ float  sscal;
  __shared__ float4 pacc[32][8];

  float m = -1e30f;
  for (int i = tid; i < L_; i += 256) {
    float v = logits[(size_t)bh * L_ + i] +
              logits[(size_t)(128 * L_) + bh * L_ + i];
    sl[i] = v;
    m = fmaxf(m, v);
  }
#pragma unroll
  for (int off = 32; off > 0; off >>= 1) m = fmaxf(m, __shfl_xor(m, off));
  if ((tid & 63) == 0) sred[tid >> 6] = m;
  __syncthreads();
  if (tid == 0) {
    float mm = fmaxf(fmaxf(sred[0], sred[1]), fmaxf(sred[2], sred[3]));
    sscal = mm;
  }
  __syncthreads();
  const float mx = sscal;

  float s = 0.f;
  for (int i = tid; i < L_; i += 256) {
    float e = __expf(sl[i] - mx);
    sl[i] = e;
    s += e;
  }
#pragma unroll
  for (int off = 32; off > 0; off >>= 1) s += __shfl_xor(s, off);
  if ((tid & 63) == 0) sred[tid >> 6] = s;
  __syncthreads();
  if (tid == 0) {
    sscal = 1.0f / ((sred[0] + sred[1]) + (sred[2] + sred[3]));
  }
  __syncthreads();
  const float inv = sscal;

  // PV over 32 cols: 8 float4-cols x 32 l-subsets
  const int dq4  = tid & 7;
  const int lsub = tid >> 3;
  const float4* vp = (const float4*)(values + (size_t)b * H_ + head * DK + dpart * 32) + dq4;
  float4 acc = {0.f, 0.f, 0.f, 0.f};
  for (int ll = lsub; ll < L_; ll += 32) {
    const float w = sl[ll];
    float4 v = vp[(size_t)ll * (B_ * H_ / 4)];
    acc.x += w * v.x; acc.y += w * v.y; acc.z += w * v.z; acc.w += w * v.w;
  }
  pacc[lsub][dq4] = acc;
  __syncthreads();
  if (tid < 64) {
    const int q = tid & 7, k = tid >> 3;
    float4 a0 = pacc[k][q], a1 = pacc[k + 8][q], a2 = pacc[k + 16][q], a3 = pacc[k + 24][q];
    float4 r;
    r.x = (a0.x + a1.x) + (a2.x + a3.x);
    r.y = (a0.y + a1.y) + (a2.y + a3.y);
    r.z = (a0.z + a1.z) + (a2.z + a3.z);
    r.w = (a0.w + a1.w) + (a2.w + a3.w);
    pacc[k][q] = r;
  }
  __syncthreads();
  if (tid < 8) {
    float4 t = {0.f, 0.f, 0.f, 0.f};
#pragma unroll
    for (int k = 0; k < 8; ++k) {
      float4 a = pacc[k][tid];
      t.x += a.x; t.y += a.y; t.z += a.z; t.w += a.w;
    }
    t.x *= inv; t.y *= inv; t.z *= inv; t.w *= inv;
    *(float4*)(out + (size_t)b * H_ + head * DK + dpart * 32 + tid * 4) = t;
  }
}

// ---------------------------------------------------------------------------
extern "C" void kernel_launch(void* const* d_in, const int* in_sizes, int n_in,
                              void* d_out, int out_size, void* d_ws, size_t ws_size,
                              hipStream_t stream) {
  const float* query  = (const float*)d_in[0];
  const float* feed   = (const float*)d_in[1];
  const float* values = (const float*)d_in[2];
  const float* attn_w = (const float*)d_in[3];
  const float* bias   = (const float*)d_in[4];
  const float* score  = (const float*)d_in[5];
  float* out = (float*)d_out;

  // Workspace: qs2 (2 MB float2) | wktf (512 KB bf16) | logits[2] (2x512 KB)
  float2* qs2    = (float2*)d_ws;
  __bf16* wktf   = (__bf16*)((char*)d_ws + (size_t)(B_ * HEADS * H_) * sizeof(float2));
  float*  logits = (float*)((char*)wktf + (size_t)(H_ * DK) * sizeof(__bf16));

  prep_kernel<<<144, 256, 0, stream>>>(query, attn_w, bias, score, qs2, wktf);
  logits_kernel<<<dim3(L_ / 256, B_ * HEADS, 2), 256, 0, stream>>>(feed, wktf, qs2, logits);
  softmax_pv_kernel<<<dim3(B_ * HEADS, 4), 256, 0, stream>>>(logits, values, out);
}

// Round 15
// 102.693 us; speedup vs baseline: 2.7851x; 2.7851x over previous
//
#include <hip/hip_runtime.h>
#include <hip/hip_bf16.h>

#define HEADS 16
#define B_    8
#define H_    2048
#define L_    1024
#define DK    128   // H_/HEADS

typedef __attribute__((ext_vector_type(8))) __bf16 bf16x8;
typedef __attribute__((ext_vector_type(4))) float  f32x4;

// ---------------------------------------------------------------------------
// Kernel 0 (merged preps).
// Blocks 0..127:   qs2[bh][j] = { q.Wq + bias, score[j] }  (float2)
// Blocks 128..143: wktf fragment-order pack of Wk (bf16):
//   wktf[(nc*256 + ks*64 + lane)*8 + i] = Wk[k][n],
//   n = nc*16 + (lane&15), k = ks*32 + (lane>>4)*8 + i
// ---------------------------------------------------------------------------
__global__ void __launch_bounds__(256)
prep_kernel(const float* __restrict__ query,
            const float* __restrict__ attn_w,
            const float* __restrict__ bias,
            const float* __restrict__ score,
            float2* __restrict__ qs2,
            __bf16* __restrict__ wktf) {
  const int tid = threadIdx.x;
  if (blockIdx.x < 128) {
    const int jt = blockIdx.x & 7;    // j-tile
    const int bg = blockIdx.x >> 3;   // bh-group of 8
    __shared__ float qv[8][DK];
    for (int i = tid; i < 8 * DK; i += 256) {
      const int bh = bg * 8 + (i >> 7);
      const int d  = i & 127;
      const int b = bh >> 4, head = bh & 15;
      qv[i >> 7][d] = query[b * H_ + head * DK + d];
    }
    __syncthreads();
    const int j = jt * 256 + tid;
    const float bj = bias[j];
    const float sj = score[j];
    float acc[8];
#pragma unroll
    for (int u = 0; u < 8; ++u) acc[u] = bj;
    for (int d = 0; d < DK; ++d) {
      const float wv = attn_w[d * H_ + j];
#pragma unroll
      for (int u = 0; u < 8; ++u) acc[u] += qv[u][d] * wv;
    }
#pragma unroll
    for (int u = 0; u < 8; ++u) {
      float2 t; t.x = acc[u]; t.y = sj;
      qs2[(size_t)(bg * 8 + u) * H_ + j] = t;
    }
  } else {
    const int t0 = (blockIdx.x - 128) * 256 + tid;   // 0..4095
    for (int tt = t0; tt < 32768; tt += 4096) {
      const int lane2  = tt & 63;
      const int chunk2 = tt >> 6;
      const int ks = chunk2 & 3;
      const int nc = chunk2 >> 2;
      const int row = lane2 & 15, g = lane2 >> 4;
      const int n  = nc * 16 + row;
      const int k0 = ks * 32 + g * 8;
      bf16x8 v;
#pragma unroll
      for (int i = 0; i < 8; ++i)
        v[i] = (__bf16)attn_w[(size_t)(DK + k0 + i) * H_ + n];
      *(bf16x8*)(wktf + (size_t)tt * 8) = v;
    }
  }
}

// ---------------------------------------------------------------------------
// Kernel 1: partial logits over one H-half.
// NO LDS, NO barriers. Block = 4 fully independent waves x 64 rows; each
// block covers 64 n-chunks (one half). aF[4][4] resident (64 VGPR).
// B + {qwb,score} stream L2->registers, 2-stage pipeline pinned by
// sched_barrier(0). Grid (4,128,2) = 1024 blocks -> 4 blocks/CU.
// launch_bounds(256,2): lets the allocator find the proven ~84-reg
// spill-free allocation (round 13); 84 <= 128 so the HW still co-schedules
// 4 waves/SIMD. (256,4) clamped to 64 VGPR and spilled 252 MB — never again.
// ---------------------------------------------------------------------------
__global__ void __launch_bounds__(256, 2)
logits_kernel(const float* __restrict__ feed,
              const __bf16* __restrict__ wktf,
              const float2* __restrict__ qs2,
              float* __restrict__ logits) {
  const int ltile = blockIdx.x;     // 0..3 (256 rows each)
  const int bh    = blockIdx.y;     // 0..127
  const int nblk  = blockIdx.z;     // 0..1 (H halves)
  const int b     = bh >> 4;
  const int head  = bh & 15;
  const int tid   = threadIdx.x;
  const int wave  = tid >> 6;
  const int lane  = tid & 63;
  const int row   = lane & 15;      // A row / B col / D col
  const int g     = lane >> 4;      // k-group 0..3

  // ---- A fragments: 4 subtiles x 4 k-steps, resident in registers ----
  bf16x8 aF[4][4];
#pragma unroll
  for (int s = 0; s < 4; ++s) {
    const int l = ltile * 256 + wave * 64 + s * 16 + row;
    const float* fh = feed + (size_t)l * (B_ * H_) + b * H_ + head * DK;
#pragma unroll
    for (int ks = 0; ks < 4; ++ks) {
      const int k0 = ks * 32 + g * 8;
      float4 x = *(const float4*)(fh + k0);
      float4 y = *(const float4*)(fh + k0 + 4);
      bf16x8 t;
      t[0] = (__bf16)x.x; t[1] = (__bf16)x.y; t[2] = (__bf16)x.z; t[3] = (__bf16)x.w;
      t[4] = (__bf16)y.x; t[5] = (__bf16)y.y; t[6] = (__bf16)y.z; t[7] = (__bf16)y.w;
      aF[s][ks] = t;
    }
  }

  // per-half bases: 64 chunks x 4KB = 256KB = 16384 bf16x8
  const bf16x8* wb = (const bf16x8*)wktf + (size_t)nblk * 16384 + lane;
  const float2* qp = qs2 + (size_t)bh * H_ + nblk * 1024 + row;

  float lacc[4][4] = {};
  bf16x8 a0, a1, a2, a3, b0, b1, b2, b3;
  float2 qA, qB;

#define LOADC(c_, x0_, x1_, x2_, x3_, q_) {                                   \
    const bf16x8* p = wb + (size_t)(c_) * 256;                                \
    x0_ = p[0]; x1_ = p[64]; x2_ = p[128]; x3_ = p[192];                      \
    q_ = qp[(c_) * 16];                                                       \
  }

#define COMPC(x0_, x1_, x2_, x3_, q_) {                                       \
    const float qx = q_.x, qy = q_.y;                                         \
    f32x4 d0 = {qx, qx, qx, qx};                                              \
    f32x4 d1 = {qx, qx, qx, qx};                                              \
    f32x4 d2 = {qx, qx, qx, qx};                                              \
    f32x4 d3 = {qx, qx, qx, qx};                                              \
    d0 = __builtin_amdgcn_mfma_f32_16x16x32_bf16(aF[0][0], x0_, d0, 0, 0, 0); \
    d1 = __builtin_amdgcn_mfma_f32_16x16x32_bf16(aF[1][0], x0_, d1, 0, 0, 0); \
    d2 = __builtin_amdgcn_mfma_f32_16x16x32_bf16(aF[2][0], x0_, d2, 0, 0, 0); \
    d3 = __builtin_amdgcn_mfma_f32_16x16x32_bf16(aF[3][0], x0_, d3, 0, 0, 0); \
    d0 = __builtin_amdgcn_mfma_f32_16x16x32_bf16(aF[0][1], x1_, d0, 0, 0, 0); \
    d1 = __builtin_amdgcn_mfma_f32_16x16x32_bf16(aF[1][1], x1_, d1, 0, 0, 0); \
    d2 = __builtin_amdgcn_mfma_f32_16x16x32_bf16(aF[2][1], x1_, d2, 0, 0, 0); \
    d3 = __builtin_amdgcn_mfma_f32_16x16x32_bf16(aF[3][1], x1_, d3, 0, 0, 0); \
    d0 = __builtin_amdgcn_mfma_f32_16x16x32_bf16(aF[0][2], x2_, d0, 0, 0, 0); \
    d1 = __builtin_amdgcn_mfma_f32_16x16x32_bf16(aF[1][2], x2_, d1, 0, 0, 0); \
    d2 = __builtin_amdgcn_mfma_f32_16x16x32_bf16(aF[2][2], x2_, d2, 0, 0, 0); \
    d3 = __builtin_amdgcn_mfma_f32_16x16x32_bf16(aF[3][2], x2_, d3, 0, 0, 0); \
    d0 = __builtin_amdgcn_mfma_f32_16x16x32_bf16(aF[0][3], x3_, d0, 0, 0, 0); \
    d1 = __builtin_amdgcn_mfma_f32_16x16x32_bf16(aF[1][3], x3_, d1, 0, 0, 0); \
    d2 = __builtin_amdgcn_mfma_f32_16x16x32_bf16(aF[2][3], x3_, d2, 0, 0, 0); \
    d3 = __builtin_amdgcn_mfma_f32_16x16x32_bf16(aF[3][3], x3_, d3, 0, 0, 0); \
    _Pragma("unroll")                                                         \
    for (int i = 0; i < 4; ++i) {                                             \
      lacc[0][i] += fmaxf(d0[i], 0.f) * qy;                                   \
      lacc[1][i] += fmaxf(d1[i], 0.f) * qy;                                   \
      lacc[2][i] += fmaxf(d2[i], 0.f) * qy;                                   \
      lacc[3][i] += fmaxf(d3[i], 0.f) * qy;                                   \
    }                                                                         \
  }

  LOADC(0, a0, a1, a2, a3, qA);
#pragma unroll 1
  for (int c = 0; c < 64; c += 2) {
    LOADC(c + 1, b0, b1, b2, b3, qB);
    __builtin_amdgcn_sched_barrier(0);    // prefetch stays ABOVE this compute
    COMPC(a0, a1, a2, a3, qA);
    const int cn = (c + 2 < 64) ? c + 2 : 63;  // tail: redundant, harmless
    LOADC(cn, a0, a1, a2, a3, qA);
    __builtin_amdgcn_sched_barrier(0);
    COMPC(b0, b1, b2, b3, qB);
  }

  // ---- reduce over the 16 D-columns, write partial logits ----
#pragma unroll
  for (int s = 0; s < 4; ++s) {
#pragma unroll
    for (int i = 0; i < 4; ++i) {
      float v = lacc[s][i];
#pragma unroll
      for (int off = 1; off < 16; off <<= 1) v += __shfl_xor(v, off);
      lacc[s][i] = v;
    }
  }
  if (row == 0) {
    float* lout = logits + (size_t)nblk * (128 * L_);
#pragma unroll
    for (int s = 0; s < 4; ++s) {
      const int base = bh * L_ + ltile * 256 + wave * 64 + s * 16 + g * 4;
#pragma unroll
      for (int i = 0; i < 4; ++i) lout[base + i] = lacc[s][i];
    }
  }
}

// ---------------------------------------------------------------------------
// Kernel 2: grid (bh, dpart): softmax over L (sum of the two H-half partial
// buffers, redundant per dpart), then out[d] over 32 d-columns. float4 reads.
// ---------------------------------------------------------------------------
__global__ void __launch_bounds__(256)
softmax_pv_kernel(const float* __restrict__ logits,
                  const float* __restrict__ values,
                  float* __restrict__ out) {
  const int bh    = blockIdx.x;   // 0..127
  const int dpart = blockIdx.y;   // 0..3  (32 d-cols each)
  const int b     = bh >> 4;
  const int head  = bh & 15;
  const int tid   = threadIdx.x;

  __shared__ float  sl[L_];
  __shared__ float  sred[4];
  __shared__ float  sscal;
  __shared__ float4 pacc[32][8];

  float m = -1e30f;
  for (int i = tid; i < L_; i += 256) {
    float v = logits[(size_t)bh * L_ + i] +
              logits[(size_t)(128 * L_) + bh * L_ + i];
    sl[i] = v;
    m = fmaxf(m, v);
  }
#pragma unroll
  for (int off = 32; off > 0; off >>= 1) m = fmaxf(m, __shfl_xor(m, off));
  if ((tid & 63) == 0) sred[tid >> 6] = m;
  __syncthreads();
  if (tid == 0) {
    float mm = fmaxf(fmaxf(sred[0], sred[1]), fmaxf(sred[2], sred[3]));
    sscal = mm;
  }
  __syncthreads();
  const float mx = sscal;

  float s = 0.f;
  for (int i = tid; i < L_; i += 256) {
    float e = __expf(sl[i] - mx);
    sl[i] = e;
    s += e;
  }
#pragma unroll
  for (int off = 32; off > 0; off >>= 1) s += __shfl_xor(s, off);
  if ((tid & 63) == 0) sred[tid >> 6] = s;
  __syncthreads();
  if (tid == 0) {
    sscal = 1.0f / ((sred[0] + sred[1]) + (sred[2] + sred[3]));
  }
  __syncthreads();
  const float inv = sscal;

  // PV over 32 cols: 8 float4-cols x 32 l-subsets
  const int dq4  = tid & 7;
  const int lsub = tid >> 3;
  const float4* vp = (const float4*)(values + (size_t)b * H_ + head * DK + dpart * 32) + dq4;
  float4 acc = {0.f, 0.f, 0.f, 0.f};
  for (int ll = lsub; ll < L_; ll += 32) {
    const float w = sl[ll];
    float4 v = vp[(size_t)ll * (B_ * H_ / 4)];
    acc.x += w * v.x; acc.y += w * v.y; acc.z += w * v.z; acc.w += w * v.w;
  }
  pacc[lsub][dq4] = acc;
  __syncthreads();
  if (tid < 64) {
    const int q = tid & 7, k = tid >> 3;
    float4 a0 = pacc[k][q], a1 = pacc[k + 8][q], a2 = pacc[k + 16][q], a3 = pacc[k + 24][q];
    float4 r;
    r.x = (a0.x + a1.x) + (a2.x + a3.x);
    r.y = (a0.y + a1.y) + (a2.y + a3.y);
    r.z = (a0.z + a1.z) + (a2.z + a3.z);
    r.w = (a0.w + a1.w) + (a2.w + a3.w);
    pacc[k][q] = r;
  }
  __syncthreads();
  if (tid < 8) {
    float4 t = {0.f, 0.f, 0.f, 0.f};
#pragma unroll
    for (int k = 0; k < 8; ++k) {
      float4 a = pacc[k][tid];
      t.x += a.x; t.y += a.y; t.z += a.z; t.w += a.w;
    }
    t.x *= inv; t.y *= inv; t.z *= inv; t.w *= inv;
    *(float4*)(out + (size_t)b * H_ + head * DK + dpart * 32 + tid * 4) = t;
  }
}

// ---------------------------------------------------------------------------
extern "C" void kernel_launch(void* const* d_in, const int* in_sizes, int n_in,
                              void* d_out, int out_size, void* d_ws, size_t ws_size,
                              hipStream_t stream) {
  const float* query  = (const float*)d_in[0];
  const float* feed   = (const float*)d_in[1];
  const float* values = (const float*)d_in[2];
  const float* attn_w = (const float*)d_in[3];
  const float* bias   = (const float*)d_in[4];
  const float* score  = (const float*)d_in[5];
  float* out = (float*)d_out;

  // Workspace: qs2 (2 MB float2) | wktf (512 KB bf16) | logits[2] (2x512 KB)
  float2* qs2    = (float2*)d_ws;
  __bf16* wktf   = (__bf16*)((char*)d_ws + (size_t)(B_ * HEADS * H_) * sizeof(float2));
  float*  logits = (float*)((char*)wktf + (size_t)(H_ * DK) * sizeof(__bf16));

  prep_kernel<<<144, 256, 0, stream>>>(query, attn_w, bias, score, qs2, wktf);
  logits_kernel<<<dim3(L_ / 256, B_ * HEADS, 2), 256, 0, stream>>>(feed, wktf, qs2, logits);
  softmax_pv_kernel<<<dim3(B_ * HEADS, 4), 256, 0, stream>>>(logits, values, out);
}